// Round 1
// baseline (1037.169 us; speedup 1.0000x reference)
//
#include <hip/hip_runtime.h>
#include <math.h>

// GAT_45810121179415 — round 1: correct fp32 baseline, fully fused.
// Layer1: grid 2048 blocks x 256 thr; each wave = one (b,n2) group of 16 rows.
// Layer2: grid 512 blocks x 256 thr; one block per b, one wave per head.

__device__ __forceinline__ float gelu_exact(float v) {
    // tf/jax exact gelu: 0.5*x*(1+erf(x/sqrt(2)))
    return 0.5f * v * (1.0f + erff(v * 0.7071067811865476f));
}

__device__ __forceinline__ float wave_sum64(float v) {
#pragma unroll
    for (int m = 32; m >= 1; m >>= 1) v += __shfl_xor(v, m, 64);
    return v;
}

// acc[j] (j -> col d = 4*lane+j) += xv[r] * W[k4*4+r][4*lane+j]
__device__ __forceinline__ void fma16(float* __restrict__ a, const float4 xv,
                                      const float4 w0, const float4 w1,
                                      const float4 w2, const float4 w3) {
    a[0] = fmaf(xv.x, w0.x, a[0]); a[0] = fmaf(xv.y, w1.x, a[0]);
    a[0] = fmaf(xv.z, w2.x, a[0]); a[0] = fmaf(xv.w, w3.x, a[0]);
    a[1] = fmaf(xv.x, w0.y, a[1]); a[1] = fmaf(xv.y, w1.y, a[1]);
    a[1] = fmaf(xv.z, w2.y, a[1]); a[1] = fmaf(xv.w, w3.y, a[1]);
    a[2] = fmaf(xv.x, w0.z, a[2]); a[2] = fmaf(xv.y, w1.z, a[2]);
    a[2] = fmaf(xv.z, w2.z, a[2]); a[2] = fmaf(xv.w, w3.z, a[2]);
    a[3] = fmaf(xv.x, w0.w, a[3]); a[3] = fmaf(xv.y, w1.w, a[3]);
    a[3] = fmaf(xv.z, w2.w, a[3]); a[3] = fmaf(xv.w, w3.w, a[3]);
}

// ---------------- Layer 1 ----------------
// x: [512,16,16,256]  W0: [4,256,256]  A0: [4,512]  y1(out): [512,16,256]
__global__ __launch_bounds__(256) void gat_l1(const float* __restrict__ x,
                                              const float* __restrict__ W0,
                                              const float* __restrict__ A0,
                                              float* __restrict__ y1) {
    __shared__ float4 xs[4][1024];  // [wave][n*64 + k4], 64 KB
    const int wave = threadIdx.x >> 6;
    const int lane = threadIdx.x & 63;
    const int gid  = (blockIdx.x << 2) | wave;  // (b*16 + n2) in [0, 8192)

    // stage this wave's 16x256 x-tile (pure linear copy, coalesced float4)
    const float4* xg = (const float4*)x + (size_t)gid * 1024;
#pragma unroll
    for (int i = 0; i < 16; ++i)
        xs[wave][(i << 6) | lane] = xg[(i << 6) | lane];
    __syncthreads();

    float out[4] = {0.f, 0.f, 0.f, 0.f};

#pragma unroll 1
    for (int h = 0; h < 4; ++h) {
        const float4* Wh = (const float4*)(W0 + (h << 16));  // [256][64] float4
        float acc[16][4];
#pragma unroll
        for (int n = 0; n < 16; ++n) {
            acc[n][0] = 0.f; acc[n][1] = 0.f; acc[n][2] = 0.f; acc[n][3] = 0.f;
        }

        // wx = x_tile @ W0[h]; thread owns cols d = 4*lane + j
#pragma unroll 2
        for (int k4 = 0; k4 < 64; ++k4) {
            const float4 w0 = Wh[((k4 << 2) + 0) * 64 + lane];
            const float4 w1 = Wh[((k4 << 2) + 1) * 64 + lane];
            const float4 w2 = Wh[((k4 << 2) + 2) * 64 + lane];
            const float4 w3 = Wh[((k4 << 2) + 3) * 64 + lane];
#pragma unroll
            for (int n = 0; n < 16; ++n)
                fma16(acc[n], xs[wave][(n << 6) | k4], w0, w1, w2, w3);
        }

        // z[n] = dot(cat(wx[n], wx[0]), A0[h])
        const float4 alo = ((const float4*)(A0 + (h << 9)))[lane];
        const float4 ahi = ((const float4*)(A0 + (h << 9) + 256))[lane];
        const float rootd = acc[0][0] * ahi.x + acc[0][1] * ahi.y +
                            acc[0][2] * ahi.z + acc[0][3] * ahi.w;
        float z[16];
#pragma unroll
        for (int n = 0; n < 16; ++n) {
            float v = acc[n][0] * alo.x + acc[n][1] * alo.y +
                      acc[n][2] * alo.z + acc[n][3] * alo.w + rootd;
            z[n] = wave_sum64(v);
        }
        // att = softmax(gelu(gelu(z))) over n
        float m = -1e30f;
#pragma unroll
        for (int n = 0; n < 16; ++n) {
            z[n] = gelu_exact(gelu_exact(z[n]));
            m = fmaxf(m, z[n]);
        }
        float s = 0.f;
#pragma unroll
        for (int n = 0; n < 16; ++n) { z[n] = expf(z[n] - m); s += z[n]; }
        const float inv = 1.0f / s;
        // out_head[d] = gelu(sum_n wx[n,d]*att[n]); mean over heads
#pragma unroll
        for (int j = 0; j < 4; ++j) {
            float t = 0.f;
#pragma unroll
            for (int n = 0; n < 16; ++n) t = fmaf(acc[n][j], z[n], t);
            out[j] += 0.25f * gelu_exact(t * inv);
        }
    }

    ((float4*)y1)[(size_t)gid * 64 + lane] =
        make_float4(out[0], out[1], out[2], out[3]);
}

// ---------------- Layer 2 ----------------
// y1: [512,16,256]  W1: [4,256,256]  A1: [4,512]  out: [512,256]
__global__ __launch_bounds__(256) void gat_l2(const float* __restrict__ y1,
                                              const float* __restrict__ W1,
                                              const float* __restrict__ A1,
                                              float* __restrict__ out) {
    __shared__ float4 xs[1024];     // [n2*64 + k4], 16 KB (shared by all waves)
    __shared__ float gh[4][256];    // per-head gelu'd outputs
    const int wave = threadIdx.x >> 6;  // = head h
    const int lane = threadIdx.x & 63;
    const int b = blockIdx.x;

    const float4* xg = (const float4*)y1 + (size_t)b * 1024;
#pragma unroll
    for (int i = 0; i < 4; ++i)
        xs[(i << 8) | threadIdx.x] = xg[(i << 8) | threadIdx.x];
    __syncthreads();

    const int h = wave;
    const float4* Wh = (const float4*)(W1 + (h << 16));
    float acc[16][4];
#pragma unroll
    for (int n = 0; n < 16; ++n) {
        acc[n][0] = 0.f; acc[n][1] = 0.f; acc[n][2] = 0.f; acc[n][3] = 0.f;
    }

#pragma unroll 2
    for (int k4 = 0; k4 < 64; ++k4) {
        const float4 w0 = Wh[((k4 << 2) + 0) * 64 + lane];
        const float4 w1 = Wh[((k4 << 2) + 1) * 64 + lane];
        const float4 w2 = Wh[((k4 << 2) + 2) * 64 + lane];
        const float4 w3 = Wh[((k4 << 2) + 3) * 64 + lane];
#pragma unroll
        for (int n = 0; n < 16; ++n)
            fma16(acc[n], xs[(n << 6) | k4], w0, w1, w2, w3);
    }

    const float4 alo = ((const float4*)(A1 + (h << 9)))[lane];
    const float4 ahi = ((const float4*)(A1 + (h << 9) + 256))[lane];
    const float rootd = acc[0][0] * ahi.x + acc[0][1] * ahi.y +
                        acc[0][2] * ahi.z + acc[0][3] * ahi.w;
    float z[16];
#pragma unroll
    for (int n = 0; n < 16; ++n) {
        float v = acc[n][0] * alo.x + acc[n][1] * alo.y +
                  acc[n][2] * alo.z + acc[n][3] * alo.w + rootd;
        z[n] = wave_sum64(v);
    }
    float m = -1e30f;
#pragma unroll
    for (int n = 0; n < 16; ++n) {
        z[n] = gelu_exact(gelu_exact(z[n]));
        m = fmaxf(m, z[n]);
    }
    float s = 0.f;
#pragma unroll
    for (int n = 0; n < 16; ++n) { z[n] = expf(z[n] - m); s += z[n]; }
    const float inv = 1.0f / s;
    float g[4];
#pragma unroll
    for (int j = 0; j < 4; ++j) {
        float t = 0.f;
#pragma unroll
        for (int n = 0; n < 16; ++n) t = fmaf(acc[n][j], z[n], t);
        g[j] = gelu_exact(t * inv);
    }
    ((float4*)&gh[h][0])[lane] = make_float4(g[0], g[1], g[2], g[3]);
    __syncthreads();

    const int t = threadIdx.x;
    out[(size_t)b * 256 + t] =
        0.25f * (gh[0][t] + gh[1][t] + gh[2][t] + gh[3][t]);
}

extern "C" void kernel_launch(void* const* d_in, const int* in_sizes, int n_in,
                              void* d_out, int out_size, void* d_ws, size_t ws_size,
                              hipStream_t stream) {
    const float* x  = (const float*)d_in[0];
    const float* W0 = (const float*)d_in[1];
    const float* A0 = (const float*)d_in[2];
    const float* W1 = (const float*)d_in[3];
    const float* A1 = (const float*)d_in[4];
    float* y1 = (float*)d_ws;  // [512*16*256] = 8 MB scratch, fully overwritten

    gat_l1<<<dim3(2048), dim3(256), 0, stream>>>(x, W0, A0, y1);
    gat_l2<<<dim3(512), dim3(256), 0, stream>>>(y1, W1, A1, (float*)d_out);
}

// Round 2
// 510.848 us; speedup vs baseline: 2.0303x; 2.0303x over previous
//
#include <hip/hip_runtime.h>
#include <math.h>

typedef _Float16 half_t;
typedef __attribute__((ext_vector_type(4))) _Float16 half4;
typedef __attribute__((ext_vector_type(8))) _Float16 half8;
typedef __attribute__((ext_vector_type(16))) float floatx16;

__device__ __forceinline__ float gelu_exact(float v) {
    return 0.5f * v * (1.0f + erff(v * 0.7071067811865476f));
}

__device__ __forceinline__ floatx16 zero16() {
    floatx16 z;
#pragma unroll
    for (int i = 0; i < 16; ++i) z[i] = 0.f;
    return z;
}

#define MFMA(a, b, c) __builtin_amdgcn_mfma_f32_32x32x16_f16((a), (b), (c), 0, 0, 0)

// ---------------- prep ----------------
// W [h][k][n] fp32 -> Wt hi/lo [h][n][k] fp16 (transposed, split)
// Za tables [32][256] fp16 hi/lo: row 2h = W[h]·A[h][0:256] (attn), 2h+1 = W[h]·A[h][256:512] (root)
__global__ __launch_bounds__(256) void prep(const float* __restrict__ W0,
                                            const float* __restrict__ A0,
                                            const float* __restrict__ W1,
                                            const float* __restrict__ A1,
                                            half_t* __restrict__ Wt0h, half_t* __restrict__ Wt0l,
                                            half_t* __restrict__ Wt1h, half_t* __restrict__ Wt1l,
                                            half_t* __restrict__ Za0h, half_t* __restrict__ Za0l,
                                            half_t* __restrict__ Za1h, half_t* __restrict__ Za1l) {
    __shared__ float tile[32][257];
    const int t = threadIdx.x;
    const int kb = blockIdx.x & 7;
    const int h  = (blockIdx.x >> 3) & 3;
    const int tz = blockIdx.x >> 5;
    const float* W = tz ? W1 : W0;
    const float* A = tz ? A1 : A0;
    half_t* Wh = tz ? Wt1h : Wt0h;
    half_t* Wl = tz ? Wt1l : Wt0l;
    half_t* Zh = tz ? Za1h : Za0h;
    half_t* Zl = tz ? Za1l : Za0l;

    // stage k-tile [32][256]: coalesced reads
    for (int i = 0; i < 32; ++i)
        tile[i][t] = W[(size_t)(h * 256 + kb * 32 + i) * 256 + t];
    __syncthreads();

    // thread t = n: write Wt[h][n][32kb .. +31] hi/lo
    half_t hb[32], lb[32];
#pragma unroll
    for (int i = 0; i < 32; ++i) {
        float v = tile[i][t];
        half_t hi = (half_t)v;
        half_t lo = (half_t)(v - (float)hi);
        hb[i] = hi; lb[i] = lo;
    }
    size_t base = (size_t)(h * 256 + t) * 256 + kb * 32;
#pragma unroll
    for (int i = 0; i < 4; ++i) {
        *(half8*)&Wh[base + 8 * i] = *(half8*)&hb[8 * i];
        *(half8*)&Wl[base + 8 * i] = *(half8*)&lb[8 * i];
    }

    if (kb == 0) {
        // wa[k] = sum_d W[h][k][d] * A[...] ; thread t = k
        const float4* Wr = (const float4*)&W[(size_t)(h * 256 + t) * 256];
        const float4* Al = (const float4*)&A[h * 512];
        const float4* Ah = (const float4*)&A[h * 512 + 256];
        float wl = 0.f, wh = 0.f;
        for (int d = 0; d < 64; ++d) {
            float4 wv = Wr[d], a0 = Al[d], a1 = Ah[d];
            wl += wv.x * a0.x + wv.y * a0.y + wv.z * a0.z + wv.w * a0.w;
            wh += wv.x * a1.x + wv.y * a1.y + wv.z * a1.z + wv.w * a1.w;
        }
        half_t hi = (half_t)wl, lo = (half_t)(wl - (float)hi);
        Zh[(2 * h) * 256 + t] = hi; Zl[(2 * h) * 256 + t] = lo;
        hi = (half_t)wh; lo = (half_t)(wh - (float)hi);
        Zh[(2 * h + 1) * 256 + t] = hi; Zl[(2 * h + 1) * 256 + t] = lo;
        if (h == 0) {
            for (int c = 8; c < 32; ++c) {
                Zh[c * 256 + t] = (half_t)0.f;
                Zl[c * 256 + t] = (half_t)0.f;
            }
        }
    }
}

// ---------------- fused GAT layer (used for both layers) ----------------
// x: [G][16][256] fp32 (G groups of 16 rows); grid = G/4 blocks of 256 thr.
// Wth/Wtl: [4][256 n][256 k] fp16; Zah/Zal: [32][256] fp16; out: [G][256] fp32.
// Per block: 64 rows. Wave w owns cols [64w,64w+64). MFMA 32x32x16 f16, 3-pass split.
__global__ __launch_bounds__(256, 2) void gat_layer(
    const float* __restrict__ x,
    const half_t* __restrict__ Wth, const half_t* __restrict__ Wtl,
    const half_t* __restrict__ Zah, const half_t* __restrict__ Zal,
    float* __restrict__ out) {
    __shared__ half_t xs_hi[64][264];   // +16B row pad for b128 bank spread
    __shared__ half_t xs_lo[64][264];
    __shared__ float zlo_s[4][64];
    __shared__ float zhi_s[4][64];
    __shared__ float ge_s[4][64];
    __shared__ float att_s[64][4];

    const int t  = threadIdx.x;
    const int w  = t >> 6;
    const int l  = t & 63;
    const int lm = l & 31;
    const int q  = l >> 5;
    const size_t rowbase = (size_t)blockIdx.x * 64;

    // ---- stage x -> LDS fp16 hi/lo split ----
    {
        const float4* xg = (const float4*)(x + rowbase * 256);
#pragma unroll
        for (int i = 0; i < 16; ++i) {
            int idx = t + 256 * i;
            int row = idx >> 6, c4 = idx & 63;
            float4 v = xg[idx];
            half_t h0 = (half_t)v.x, h1 = (half_t)v.y, h2 = (half_t)v.z, h3 = (half_t)v.w;
            half4 hv = {h0, h1, h2, h3};
            half4 lv = {(half_t)(v.x - (float)h0), (half_t)(v.y - (float)h1),
                        (half_t)(v.z - (float)h2), (half_t)(v.w - (float)h3)};
            *(half4*)&xs_hi[row][c4 * 4] = hv;
            *(half4*)&xs_lo[row][c4 * 4] = lv;
        }
    }
    __syncthreads();

    // ---- z-tile: z = x @ (W·A) for all 4 heads (cols 0..7 of Za) ----
    {
        floatx16 accz0 = zero16(), accz1 = zero16();
        const half_t* zbh = Zah + (size_t)lm * 256 + 8 * q;
        const half_t* zbl = Zal + (size_t)lm * 256 + 8 * q;
#pragma unroll 2
        for (int ks = 0; ks < 16; ++ks) {
            const int ke = 16 * ks;
            half8 ah0 = *(const half8*)&xs_hi[lm][ke + 8 * q];
            half8 ah1 = *(const half8*)&xs_hi[32 + lm][ke + 8 * q];
            half8 al0 = *(const half8*)&xs_lo[lm][ke + 8 * q];
            half8 al1 = *(const half8*)&xs_lo[32 + lm][ke + 8 * q];
            half8 bh = *(const half8*)(zbh + ke);
            half8 bl = *(const half8*)(zbl + ke);
            accz0 = MFMA(ah0, bh, accz0); accz1 = MFMA(ah1, bh, accz1);
            accz0 = MFMA(al0, bh, accz0); accz1 = MFMA(al1, bh, accz1);
            accz0 = MFMA(ah0, bl, accz0); accz1 = MFMA(ah1, bl, accz1);
        }
        if (w == 0 && lm < 8) {
            int h = lm >> 1;
            float* dst = (lm & 1) ? &zhi_s[h][0] : &zlo_s[h][0];
#pragma unroll
            for (int r = 0; r < 16; ++r) {
                int row0 = 4 * q + (r & 3) + 8 * (r >> 2);
                dst[row0] = accz0[r];
                dst[32 + row0] = accz1[r];
            }
        }
    }
    __syncthreads();

    // ---- attention weights for all 4 heads ----
    {
        int h = t >> 6, r = t & 63;
        float z = zlo_s[h][r] + zhi_s[h][r & 48];   // + root term
        ge_s[h][r] = gelu_exact(gelu_exact(z));
    }
    __syncthreads();
    {
        int h = t >> 6, r = t & 63, g0 = r & 48;
        float mx = -1e30f;
#pragma unroll
        for (int i = 0; i < 16; ++i) mx = fmaxf(mx, ge_s[h][g0 + i]);
        float s = 0.f;
#pragma unroll
        for (int i = 0; i < 16; ++i) s += expf(ge_s[h][g0 + i] - mx);
        att_s[r][h] = expf(ge_s[h][r] - mx) / s;
    }
    __syncthreads();

    // ---- main GEMM: heads in pairs, 3-pass split MFMA ----
    float outacc[4][2] = {{0.f, 0.f}, {0.f, 0.f}, {0.f, 0.f}, {0.f, 0.f}};
    const half_t* wbase_h = Wth + (size_t)(64 * w + lm) * 256 + 8 * q;
    const half_t* wbase_l = Wtl + (size_t)(64 * w + lm) * 256 + 8 * q;

#pragma unroll 1
    for (int hp = 0; hp < 2; ++hp) {
        floatx16 acc[4][2];  // [nt: (head-in-pair)*2 + colblk][Mt]
#pragma unroll
        for (int nt = 0; nt < 4; ++nt) { acc[nt][0] = zero16(); acc[nt][1] = zero16(); }
        const size_t hoff = (size_t)hp * 131072;

#pragma unroll 2
        for (int ks = 0; ks < 16; ++ks) {
            const int ke = 16 * ks;
            half8 ah0 = *(const half8*)&xs_hi[lm][ke + 8 * q];
            half8 ah1 = *(const half8*)&xs_hi[32 + lm][ke + 8 * q];
            half8 al0 = *(const half8*)&xs_lo[lm][ke + 8 * q];
            half8 al1 = *(const half8*)&xs_lo[32 + lm][ke + 8 * q];
#pragma unroll
            for (int nt = 0; nt < 4; ++nt) {
                const size_t o = hoff + (size_t)(nt >> 1) * 65536 + (size_t)(nt & 1) * 8192 + ke;
                half8 bh = *(const half8*)(wbase_h + o);
                half8 bl = *(const half8*)(wbase_l + o);
                acc[nt][0] = MFMA(ah0, bh, acc[nt][0]);
                acc[nt][1] = MFMA(ah1, bh, acc[nt][1]);
                acc[nt][0] = MFMA(al0, bh, acc[nt][0]);
                acc[nt][1] = MFMA(al1, bh, acc[nt][1]);
                acc[nt][0] = MFMA(ah0, bl, acc[nt][0]);
                acc[nt][1] = MFMA(ah1, bl, acc[nt][1]);
            }
        }

        // ---- weighted sum over rows with att, gelu, head-mean accumulate ----
        float tp[4][4];  // [nt][g]
#pragma unroll
        for (int nt = 0; nt < 4; ++nt)
#pragma unroll
            for (int g = 0; g < 4; ++g) tp[nt][g] = 0.f;
#pragma unroll
        for (int mt = 0; mt < 2; ++mt)
#pragma unroll
            for (int r = 0; r < 16; ++r) {
                int row = 32 * mt + 4 * q + (r & 3) + 8 * (r >> 2);
                float2 a2 = *(const float2*)&att_s[row][2 * hp];
                int g = row >> 4;
                tp[0][g] = fmaf(acc[0][mt][r], a2.x, tp[0][g]);
                tp[1][g] = fmaf(acc[1][mt][r], a2.x, tp[1][g]);
                tp[2][g] = fmaf(acc[2][mt][r], a2.y, tp[2][g]);
                tp[3][g] = fmaf(acc[3][mt][r], a2.y, tp[3][g]);
            }
#pragma unroll
        for (int nt = 0; nt < 4; ++nt)
#pragma unroll
            for (int g = 0; g < 4; ++g) {
                float s = tp[nt][g] + __shfl_xor(tp[nt][g], 32, 64);
                outacc[g][nt & 1] += 0.25f * gelu_exact(s);
            }
    }

    // ---- store (lanes 0..31 hold both col-blocks) ----
    if (q == 0) {
#pragma unroll
        for (int g = 0; g < 4; ++g) {
            size_t ro = (rowbase / 16 + g) * 256;
            out[ro + 64 * w + lm]      = outacc[g][0];
            out[ro + 64 * w + 32 + lm] = outacc[g][1];
        }
    }
}

extern "C" void kernel_launch(void* const* d_in, const int* in_sizes, int n_in,
                              void* d_out, int out_size, void* d_ws, size_t ws_size,
                              hipStream_t stream) {
    const float* x  = (const float*)d_in[0];
    const float* W0 = (const float*)d_in[1];
    const float* A0 = (const float*)d_in[2];
    const float* W1 = (const float*)d_in[3];
    const float* A1 = (const float*)d_in[4];

    char* ws = (char*)d_ws;
    float*  y1   = (float*)ws;                           // 8 MiB: [8192][256]
    half_t* Wt0h = (half_t*)(ws + 8388608);              // 512 KiB each
    half_t* Wt0l = (half_t*)(ws + 8912896);
    half_t* Wt1h = (half_t*)(ws + 9437184);
    half_t* Wt1l = (half_t*)(ws + 9961472);
    half_t* Za0h = (half_t*)(ws + 10485760);             // 16 KiB each
    half_t* Za0l = (half_t*)(ws + 10502144);
    half_t* Za1h = (half_t*)(ws + 10518528);
    half_t* Za1l = (half_t*)(ws + 10534912);

    prep<<<64, 256, 0, stream>>>(W0, A0, W1, A1, Wt0h, Wt0l, Wt1h, Wt1l,
                                 Za0h, Za0l, Za1h, Za1l);
    gat_layer<<<2048, 256, 0, stream>>>(x, Wt0h, Wt0l, Za0h, Za0l, y1);
    gat_layer<<<128, 256, 0, stream>>>(y1, Wt1h, Wt1l, Za1h, Za1l, (float*)d_out);
}